// Round 1
// baseline (2863.792 us; speedup 1.0000x reference)
//
#include <hip/hip_runtime.h>

#define N_NODES 100000
#define IN_DIM 256
#define OUT_DIM 128
#define N_EDGES 3200000

// ---------------------------------------------------------------------------
// Kernel 1: out[n][c] = b[c]  (bias init; d_out is poisoned before every call)
// 100000*128 floats = 3.2M float4; 12500 blocks x 256 threads, 1 float4 each.
// ---------------------------------------------------------------------------
__global__ __launch_bounds__(256) void bias_init_kernel(const float* __restrict__ b,
                                                        float* __restrict__ out) {
    const int i = blockIdx.x * 256 + threadIdx.x;      // < 3,200,000
    const float4* b4 = (const float4*)b;               // 32 float4s, L1-hot
    ((float4*)out)[i] = b4[i & 31];
}

// ---------------------------------------------------------------------------
// Kernel 2: h = X @ W   (f32 vector GEMM; no f32 MFMA on CDNA4)
// Block: 256 thr (4 waves), 32 rows/block. A rows staged in LDS (32 KB).
// Each wave: 8 rows. Lanes 0-31 handle rows r0..r0+3, lanes 32-63 rows
// r0+4..r0+7; each lane computes 4 rows x 4 cols (float4 W load per k).
// Per k-iter per lane: 1x 16B global (L1-hot W) + 4x ds_read + 16 fma.
// ---------------------------------------------------------------------------
__global__ __launch_bounds__(256, 4) void gemm_kernel(const float* __restrict__ X,
                                                      const float* __restrict__ W,
                                                      float* __restrict__ h) {
    __shared__ float As[32 * IN_DIM];                  // 32 KB
    const int tid = threadIdx.x;
    const int row0 = blockIdx.x * 32;

    // cooperative staging: 32 rows x 256 f32 = 2048 float4, coalesced
    const float4* Xv = (const float4*)(X + (long)row0 * IN_DIM);
    float4* Asv = (float4*)As;
#pragma unroll
    for (int i = 0; i < 8; ++i)
        Asv[tid + i * 256] = Xv[tid + i * 256];
    __syncthreads();

    const int wave = tid >> 6;
    const int lane = tid & 63;
    const int half = lane >> 5;                        // 0/1
    const int c = (lane & 31) * 4;                     // col base (0..124)
    const int rloc = wave * 8 + half * 4;              // local row base

    float acc[4][4] = {};
    const float* Asr = As + rloc * IN_DIM;

#pragma unroll 4
    for (int k = 0; k < IN_DIM; ++k) {
        const float4 w4 = *(const float4*)(W + k * OUT_DIM + c);
#pragma unroll
        for (int j = 0; j < 4; ++j) {
            const float a = Asr[j * IN_DIM + k];       // 2-addr LDS broadcast (free)
            acc[j][0] += a * w4.x;
            acc[j][1] += a * w4.y;
            acc[j][2] += a * w4.z;
            acc[j][3] += a * w4.w;
        }
    }

#pragma unroll
    for (int j = 0; j < 4; ++j) {
        float4 o = make_float4(acc[j][0], acc[j][1], acc[j][2], acc[j][3]);
        *(float4*)(h + (long)(row0 + rloc + j) * OUT_DIM + c) = o;
    }
}

// ---------------------------------------------------------------------------
// Kernel 3: scatter-add  out[dst][:] += val * h[src][:]
// One wave per 8 edges; lane covers 2 contiguous cols (float2 gather,
// 2 contiguous f32 atomics -> each edge's 128 atomics span 512 B).
// unsafeAtomicAdd guarantees hardware global_atomic_add_f32 (no CAS loop).
// ---------------------------------------------------------------------------
__global__ __launch_bounds__(256) void scatter_kernel(const int* __restrict__ src,
                                                      const int* __restrict__ dst,
                                                      const float* __restrict__ vals,
                                                      const float* __restrict__ h,
                                                      float* __restrict__ out) {
    const int wave_g = blockIdx.x * 4 + (threadIdx.x >> 6);
    const int lane = threadIdx.x & 63;
    const int c = lane * 2;
    const int e0 = wave_g * 8;                         // grid sized exactly

#pragma unroll
    for (int i = 0; i < 8; ++i) {
        const int e = e0 + i;
        const int s = src[e];
        const int d = dst[e];
        const float v = vals[e];
        const float2 m = *(const float2*)(h + s * OUT_DIM + c);
        float* o = out + d * OUT_DIM + c;
        unsafeAtomicAdd(o, v * m.x);
        unsafeAtomicAdd(o + 1, v * m.y);
    }
}

// ---------------------------------------------------------------------------
extern "C" void kernel_launch(void* const* d_in, const int* in_sizes, int n_in,
                              void* d_out, int out_size, void* d_ws, size_t ws_size,
                              hipStream_t stream) {
    const float* X     = (const float*)d_in[0];   // feature_map [100000,256]
    const int*   esrc  = (const int*)d_in[1];     // edge_src [3.2M]
    const int*   edst  = (const int*)d_in[2];     // edge_dst [3.2M]
    const float* evals = (const float*)d_in[3];   // edge_vals [3.2M]
    const float* W     = (const float*)d_in[4];   // weights [256,128]
    const float* b     = (const float*)d_in[5];   // bias [128]
    float* out = (float*)d_out;                   // [100000,128]
    float* h   = (float*)d_ws;                    // scratch: 51.2 MB

    // 1) out = broadcast(b)
    bias_init_kernel<<<dim3(N_NODES * OUT_DIM / 4 / 256), dim3(256), 0, stream>>>(b, out);
    // 2) h = X @ W
    gemm_kernel<<<dim3(N_NODES / 32), dim3(256), 0, stream>>>(X, W, h);
    // 3) out[dst] += val * h[src]
    scatter_kernel<<<dim3(N_EDGES / 32), dim3(256), 0, stream>>>(esrc, edst, evals, h, out);
}

// Round 2
// 1110.604 us; speedup vs baseline: 2.5786x; 2.5786x over previous
//
#include <hip/hip_runtime.h>

#define N_NODES 100000
#define IN_DIM 256
#define OUT_DIM 128
#define N_EDGES 3200000

// ---------------------------------------------------------------------------
// Kernel: h = X @ W   (f32 vector GEMM; no f32 MFMA on CDNA4) — unchanged R1
// ---------------------------------------------------------------------------
__global__ __launch_bounds__(256, 4) void gemm_kernel(const float* __restrict__ X,
                                                      const float* __restrict__ W,
                                                      float* __restrict__ h) {
    __shared__ float As[32 * IN_DIM];                  // 32 KB
    const int tid = threadIdx.x;
    const int row0 = blockIdx.x * 32;

    const float4* Xv = (const float4*)(X + (long)row0 * IN_DIM);
    float4* Asv = (float4*)As;
#pragma unroll
    for (int i = 0; i < 8; ++i)
        Asv[tid + i * 256] = Xv[tid + i * 256];
    __syncthreads();

    const int wave = tid >> 6;
    const int lane = tid & 63;
    const int half = lane >> 5;
    const int c = (lane & 31) * 4;
    const int rloc = wave * 8 + half * 4;

    float acc[4][4] = {};
    const float* Asr = As + rloc * IN_DIM;

#pragma unroll 4
    for (int k = 0; k < IN_DIM; ++k) {
        const float4 w4 = *(const float4*)(W + k * OUT_DIM + c);
#pragma unroll
        for (int j = 0; j < 4; ++j) {
            const float a = Asr[j * IN_DIM + k];
            acc[j][0] += a * w4.x;
            acc[j][1] += a * w4.y;
            acc[j][2] += a * w4.z;
            acc[j][3] += a * w4.w;
        }
    }

#pragma unroll
    for (int j = 0; j < 4; ++j) {
        float4 o = make_float4(acc[j][0], acc[j][1], acc[j][2], acc[j][3]);
        *(float4*)(h + (long)(row0 + rloc + j) * OUT_DIM + c) = o;
    }
}

// ---------------------------------------------------------------------------
// CSR build step 1: zero the degree counters (ws is poisoned 0xAA each call)
// ---------------------------------------------------------------------------
__global__ __launch_bounds__(256) void zero_counts_kernel(int* __restrict__ counts) {
    const int i = blockIdx.x * 256 + threadIdx.x;
    if (i < N_NODES) counts[i] = 0;
}

// ---------------------------------------------------------------------------
// CSR build step 2: histogram of dst (3.2M int atomics into 400 KB, L2-hot)
// ---------------------------------------------------------------------------
__global__ __launch_bounds__(256) void hist_kernel(const int* __restrict__ dst,
                                                   int* __restrict__ counts) {
    const int e = blockIdx.x * 256 + threadIdx.x;      // grid sized exactly
    atomicAdd(&counts[dst[e]], 1);
}

// ---------------------------------------------------------------------------
// CSR build step 3: exclusive scan of counts -> row_ptr (+ mutable copy
// `offsets` consumed by the reorder pass). Single block, 1024 threads,
// ~98 elements/thread + LDS Hillis-Steele over the 1024 partials.
// ---------------------------------------------------------------------------
#define SCAN_T 1024
#define SCAN_CHUNK 98                                   // 1024*98 = 100352 >= N_NODES
__global__ __launch_bounds__(SCAN_T) void scan_kernel(const int* __restrict__ counts,
                                                      int* __restrict__ row_ptr,
                                                      int* __restrict__ offsets) {
    __shared__ int part[SCAN_T];
    const int t = threadIdx.x;
    const int beg = t * SCAN_CHUNK;
    const int end = min(beg + SCAN_CHUNK, N_NODES);

    int s = 0;
    for (int i = beg; i < end; ++i) s += counts[i];
    part[t] = s;
    __syncthreads();

    for (int off = 1; off < SCAN_T; off <<= 1) {
        const int u = (t >= off) ? part[t - off] : 0;
        __syncthreads();
        part[t] += u;
        __syncthreads();
    }
    int run = part[t] - s;                              // exclusive prefix of chunk
    for (int i = beg; i < end; ++i) {
        row_ptr[i] = run;
        offsets[i] = run;
        run += counts[i];
    }
    if (t == 0) row_ptr[N_NODES] = N_EDGES;
}

// ---------------------------------------------------------------------------
// CSR build step 4: reorder edges into dst-sorted (src, val) pairs
// ---------------------------------------------------------------------------
__global__ __launch_bounds__(256) void reorder_kernel(const int* __restrict__ src,
                                                      const int* __restrict__ dst,
                                                      const float* __restrict__ vals,
                                                      int* __restrict__ offsets,
                                                      int2* __restrict__ pairs) {
    const int e = blockIdx.x * 256 + threadIdx.x;      // grid sized exactly
    const int d = dst[e];
    const int pos = atomicAdd(&offsets[d], 1);
    pairs[pos] = make_int2(src[e], __float_as_int(vals[e]));
}

// ---------------------------------------------------------------------------
// Gather-reduce: one wave per dst node. lane covers 2 contiguous cols.
// acc init = bias; each out row written exactly once. No f32 atomics.
// pairs[j] is a wave-uniform broadcast load; h row gather is 512 B contiguous.
// ---------------------------------------------------------------------------
__global__ __launch_bounds__(256) void gather_kernel(const int* __restrict__ row_ptr,
                                                     const int2* __restrict__ pairs,
                                                     const float* __restrict__ h,
                                                     const float* __restrict__ b,
                                                     float* __restrict__ out) {
    const int node = blockIdx.x * 4 + (threadIdx.x >> 6);
    const int lane = threadIdx.x & 63;
    const int c = lane * 2;

    const int beg = row_ptr[node];
    const int end = row_ptr[node + 1];

    float2 acc = *(const float2*)(b + c);

    int j = beg;
    for (; j + 1 < end; j += 2) {                      // 2-way ILP on the gather
        const int2 p0 = pairs[j];
        const int2 p1 = pairs[j + 1];
        const float2 m0 = *(const float2*)(h + (long)p0.x * OUT_DIM + c);
        const float2 m1 = *(const float2*)(h + (long)p1.x * OUT_DIM + c);
        const float v0 = __int_as_float(p0.y);
        const float v1 = __int_as_float(p1.y);
        acc.x += v0 * m0.x;
        acc.y += v0 * m0.y;
        acc.x += v1 * m1.x;
        acc.y += v1 * m1.y;
    }
    if (j < end) {
        const int2 p0 = pairs[j];
        const float2 m0 = *(const float2*)(h + (long)p0.x * OUT_DIM + c);
        const float v0 = __int_as_float(p0.y);
        acc.x += v0 * m0.x;
        acc.y += v0 * m0.y;
    }

    *(float2*)(out + (long)node * OUT_DIM + c) = acc;
}

// ---------------------------------------------------------------------------
extern "C" void kernel_launch(void* const* d_in, const int* in_sizes, int n_in,
                              void* d_out, int out_size, void* d_ws, size_t ws_size,
                              hipStream_t stream) {
    const float* X     = (const float*)d_in[0];   // feature_map [100000,256]
    const int*   esrc  = (const int*)d_in[1];     // edge_src [3.2M]
    const int*   edst  = (const int*)d_in[2];     // edge_dst [3.2M]
    const float* evals = (const float*)d_in[3];   // edge_vals [3.2M]
    const float* W     = (const float*)d_in[4];   // weights [256,128]
    const float* b     = (const float*)d_in[5];   // bias [128]
    float* out = (float*)d_out;                   // [100000,128]

    // workspace layout (bytes):
    char* ws = (char*)d_ws;
    float* h       = (float*)(ws);                       // 51,200,000
    int2*  pairs   = (int2*) (ws + 51200000);            // 25,600,000
    int*   counts  = (int*)  (ws + 76800000);            //    400,000
    int*   row_ptr = (int*)  (ws + 77200000);            //    400,004
    int*   offsets = (int*)  (ws + 77600008);            //    400,000

    gemm_kernel<<<dim3(N_NODES / 32), dim3(256), 0, stream>>>(X, W, h);
    zero_counts_kernel<<<dim3((N_NODES + 255) / 256), dim3(256), 0, stream>>>(counts);
    hist_kernel<<<dim3(N_EDGES / 256), dim3(256), 0, stream>>>(edst, counts);
    scan_kernel<<<dim3(1), dim3(SCAN_T), 0, stream>>>(counts, row_ptr, offsets);
    reorder_kernel<<<dim3(N_EDGES / 256), dim3(256), 0, stream>>>(esrc, edst, evals, offsets, pairs);
    gather_kernel<<<dim3(N_NODES / 4), dim3(256), 0, stream>>>(row_ptr, pairs, h, b, out);
}